// Round 1
// baseline (229.724 us; speedup 1.0000x reference)
//
#include <hip/hip_runtime.h>
#include <hip/hip_bf16.h>
#include <stdint.h>

#define NN 40000
#define EE 640000
#define HD 128
#define EDIM 32
#define DDIM 32
#define TDIM 128
#define ICH 320

#define TB 64   // edges per block
#define KT 64   // k-tile
#define PAD 8   // bf16 pad: keeps 16B alignment, row stride 144B -> uniform bank spread

typedef short  s16x8 __attribute__((ext_vector_type(8)));
typedef float  f32x4 __attribute__((ext_vector_type(4)));
typedef unsigned short u16;
typedef unsigned int   u32;

__device__ __forceinline__ u16 f2b(float f) {
  union { float f; u32 u; } x; x.f = f;
  u32 r = x.u + 0x7fffu + ((x.u >> 16) & 1u);   // RNE
  return (u16)(r >> 16);
}

// ---- prep: h fp32 -> bf16 ----
__global__ void prep_h_kernel(const float* __restrict__ h, u16* __restrict__ wh) {
  int i = (blockIdx.x * 256 + threadIdx.x) * 4;
  if (i < NN * HD) {
    float4 v = *(const float4*)(h + i);
    u32 r0 = (u32)f2b(v.x) | ((u32)f2b(v.y) << 16);
    u32 r1 = (u32)f2b(v.z) | ((u32)f2b(v.w) << 16);
    *(uint2*)(wh + i) = make_uint2(r0, r1);
  }
}

// ---- prep: FiLM params t = silu(te) @ tW + tb  (256 outputs) ----
__global__ void prep_film_kernel(const float* __restrict__ te, const float* __restrict__ tW,
                                 const float* __restrict__ tb, float* __restrict__ film) {
  __shared__ float s[TDIM];
  int t = threadIdx.x;
  if (t < TDIM) { float v = te[t]; s[t] = v / (1.f + __expf(-v)); }
  __syncthreads();
  float acc = tb[t];
  #pragma unroll 8
  for (int k = 0; k < TDIM; ++k) acc += s[k] * tW[k * 256 + t];
  film[t] = acc;
}

// ---- prep: transpose W[K][128] -> Wt[128][K] bf16 ----
__global__ void prep_tr_kernel(const float* __restrict__ W, u16* __restrict__ Wt, int K) {
  int idx = blockIdx.x * 256 + threadIdx.x;
  if (idx < K * HD) {
    int k = idx >> 7, j = idx & 127;
    Wt[j * K + k] = f2b(W[idx]);
  }
}

// ---- out = pos (agg atomically added on top) ----
__global__ void copy_pos_kernel(const float* __restrict__ pos, float* __restrict__ out) {
  int i = blockIdx.x * 256 + threadIdx.x;
  if (i < NN * 3) out[i] = pos[i];
}

// ---- fused per-edge-tile kernel ----
__global__ __launch_bounds__(256) void edge_kernel(
    const float* __restrict__ pos,
    const float* __restrict__ edge_attr,
    const float* __restrict__ dist,
    const float* __restrict__ ib,
    const float* __restrict__ c1b,
    const float* __restrict__ c2w,
    const float* __restrict__ cn_scale,
    const int*   __restrict__ eidx,
    const u16*   __restrict__ wh,     // bf16 h [N][128]
    const u16*   __restrict__ wiWt,   // bf16 iW^T [128][320]
    const u16*   __restrict__ wc1Wt,  // bf16 c1W^T [128][128]
    const float* __restrict__ film,   // [256] shift|scale
    float*       __restrict__ out)
{
  __shared__ u16   sA[TB][KT + PAD];     // A k-tile (edge features, bf16)
  __shared__ u16   sW[HD][KT + PAD];     // B^T k-tile (weights, bf16)
  __shared__ u16   sX[TB][HD + PAD];     // modulated x (bf16), GEMM2 A
  __shared__ float sFilm[2 * HD];
  __shared__ float sIb[HD];
  __shared__ float sC1b[HD];
  __shared__ float sC2w[HD];
  __shared__ int   sRow[TB];
  __shared__ int   sCol[TB];
  __shared__ float sInv[TB];

  const int t    = threadIdx.x;
  const int e0   = blockIdx.x * TB;
  const int wave = t >> 6;
  const int lane = t & 63;
  const int l15  = lane & 15;
  const int lg   = lane >> 4;

  if (t < HD) {
    sIb[t]        = ib[t];
    sC1b[t]       = c1b[t];
    sC2w[t]       = c2w[t];
    sFilm[t]      = film[t];
    sFilm[HD + t] = film[HD + t];
  } else if (t < HD + TB) {
    int e = t - HD;
    sRow[e] = eidx[e0 + e];
    sCol[e] = eidx[EE + e0 + e];
  }
  __syncthreads();

  f32x4 acc[8];
  #pragma unroll
  for (int n = 0; n < 8; ++n) acc[n] = (f32x4){0.f, 0.f, 0.f, 0.f};

  const int sr = t >> 2, sq = t & 3;    // A-stage: row, 16-col quad
  const int wj = t >> 1, whf = t & 1;   // W-stage: out-channel row, 32-col half

  // ---------------- GEMM1: x = h_input @ iW, K=320 ----------------
  #pragma unroll
  for (int kt = 0; kt < 5; ++kt) {
    // stage A tile [64 edges][64 k] bf16
    if (kt < 4) {                       // k<256: gathered h rows (already bf16)
      int node = (kt < 2) ? sRow[sr] : sCol[sr];
      const u16* src = wh + (size_t)node * HD + (kt & 1) * 64 + sq * 16;
      uint4 a = *(const uint4*)src;
      uint4 b = *(const uint4*)(src + 8);
      *(uint4*)&sA[sr][sq * 16]     = a;
      *(uint4*)&sA[sr][sq * 16 + 8] = b;
    } else {                            // k 256..319: edge_attr | dist (fp32 -> bf16)
      const float* fs = (sq < 2) ? (edge_attr + (size_t)(e0 + sr) * EDIM + sq * 16)
                                 : (dist + (size_t)(e0 + sr) * DDIM + (sq - 2) * 16);
      float4 v0 = *(const float4*)(fs + 0);
      float4 v1 = *(const float4*)(fs + 4);
      float4 v2 = *(const float4*)(fs + 8);
      float4 v3 = *(const float4*)(fs + 12);
      uint4 a, b;
      a.x = (u32)f2b(v0.x) | ((u32)f2b(v0.y) << 16);
      a.y = (u32)f2b(v0.z) | ((u32)f2b(v0.w) << 16);
      a.z = (u32)f2b(v1.x) | ((u32)f2b(v1.y) << 16);
      a.w = (u32)f2b(v1.z) | ((u32)f2b(v1.w) << 16);
      b.x = (u32)f2b(v2.x) | ((u32)f2b(v2.y) << 16);
      b.y = (u32)f2b(v2.z) | ((u32)f2b(v2.w) << 16);
      b.z = (u32)f2b(v3.x) | ((u32)f2b(v3.y) << 16);
      b.w = (u32)f2b(v3.z) | ((u32)f2b(v3.w) << 16);
      *(uint4*)&sA[sr][sq * 16]     = a;
      *(uint4*)&sA[sr][sq * 16 + 8] = b;
    }
    // stage W tile: sW[j][kk] = iW^T[j][kt*64+kk]
    {
      const u16* src = wiWt + (size_t)wj * ICH + kt * KT + whf * 32;
      uint4 a = *(const uint4*)(src + 0);
      uint4 b = *(const uint4*)(src + 8);
      uint4 c = *(const uint4*)(src + 16);
      uint4 d = *(const uint4*)(src + 24);
      *(uint4*)&sW[wj][whf * 32 + 0]  = a;
      *(uint4*)&sW[wj][whf * 32 + 8]  = b;
      *(uint4*)&sW[wj][whf * 32 + 16] = c;
      *(uint4*)&sW[wj][whf * 32 + 24] = d;
    }
    __syncthreads();
    #pragma unroll
    for (int ks = 0; ks < 2; ++ks) {
      s16x8 aF = *(const s16x8*)&sA[wave * 16 + l15][ks * 32 + lg * 8];
      #pragma unroll
      for (int n = 0; n < 8; ++n) {
        s16x8 bF = *(const s16x8*)&sW[n * 16 + l15][ks * 32 + lg * 8];
        acc[n] = __builtin_amdgcn_mfma_f32_16x16x32_bf16(aF, bF, acc[n], 0, 0, 0);
      }
    }
    __syncthreads();
  }

  // ------------- LayerNorm + FiLM, write sX (bf16) -------------
  // lane holds cols {n*16+l15}, rows (lg*4+r); row stats reduce over the 16 l15-lanes
  #pragma unroll
  for (int r = 0; r < 4; ++r) {
    float s = 0.f, sq2 = 0.f;
    #pragma unroll
    for (int n = 0; n < 8; ++n) {
      float v = acc[n][r] + sIb[n * 16 + l15];
      s += v; sq2 += v * v;
    }
    #pragma unroll
    for (int m = 1; m < 16; m <<= 1) { s += __shfl_xor(s, m); sq2 += __shfl_xor(sq2, m); }
    float mean = s * (1.f / 128.f);
    float var  = sq2 * (1.f / 128.f) - mean * mean;
    float rstd = rsqrtf(var + 1e-6f);
    int   xr   = wave * 16 + lg * 4 + r;
    #pragma unroll
    for (int n = 0; n < 8; ++n) {
      int ch   = n * 16 + l15;
      float v  = acc[n][r] + sIb[ch];
      float xm = (v - mean) * rstd * (1.f + sFilm[HD + ch]) + sFilm[ch];
      sX[xr][ch] = f2b(xm);
    }
  }

  // ---------------- GEMM2: y = x_mod @ c1W, K=128 ----------------
  f32x4 acc2[8];
  #pragma unroll
  for (int n = 0; n < 8; ++n) acc2[n] = (f32x4){0.f, 0.f, 0.f, 0.f};

  #pragma unroll
  for (int kt2 = 0; kt2 < 2; ++kt2) {
    __syncthreads();   // sX writes visible (iter0) / prev MFMA done with sW (iter1)
    {
      const u16* src = wc1Wt + (size_t)wj * HD + kt2 * KT + whf * 32;
      uint4 a = *(const uint4*)(src + 0);
      uint4 b = *(const uint4*)(src + 8);
      uint4 c = *(const uint4*)(src + 16);
      uint4 d = *(const uint4*)(src + 24);
      *(uint4*)&sW[wj][whf * 32 + 0]  = a;
      *(uint4*)&sW[wj][whf * 32 + 8]  = b;
      *(uint4*)&sW[wj][whf * 32 + 16] = c;
      *(uint4*)&sW[wj][whf * 32 + 24] = d;
    }
    __syncthreads();
    #pragma unroll
    for (int ks = 0; ks < 2; ++ks) {
      s16x8 aF = *(const s16x8*)&sX[wave * 16 + l15][kt2 * KT + ks * 32 + lg * 8];
      #pragma unroll
      for (int n = 0; n < 8; ++n) {
        s16x8 bF = *(const s16x8*)&sW[n * 16 + l15][ks * 32 + lg * 8];
        acc2[n] = __builtin_amdgcn_mfma_f32_16x16x32_bf16(aF, bF, acc2[n], 0, 0, 0);
      }
    }
  }

  // ------------- silu -> dot(c2W) -> tanh -> sInv -------------
  float cns = cn_scale[0];
  #pragma unroll
  for (int r = 0; r < 4; ++r) {
    float zp = 0.f;
    #pragma unroll
    for (int n = 0; n < 8; ++n) {
      int ch  = n * 16 + l15;
      float y = acc2[n][r] + sC1b[ch];
      float sy = y / (1.f + __expf(-y));
      zp += sy * sC2w[ch];
    }
    #pragma unroll
    for (int m = 1; m < 16; m <<= 1) zp += __shfl_xor(zp, m);
    if (l15 == 0) sInv[wave * 16 + lg * 4 + r] = tanhf(zp);
  }
  __syncthreads();

  // ------------- coord_diff, normalize, scatter-add -------------
  if (t < 3 * TB) {
    int e = t / 3;
    int d = t - e * 3;
    int ri = sRow[e], ci = sCol[e];
    float ax = pos[ri * 3 + 0] - pos[ci * 3 + 0];
    float ay = pos[ri * 3 + 1] - pos[ci * 3 + 1];
    float az = pos[ri * 3 + 2] - pos[ci * 3 + 2];
    float nrm = sqrtf(ax * ax + ay * ay + az * az);
    float sc  = cns * sInv[e] / fmaxf(nrm, 1e-8f);
    float v   = (d == 0 ? ax : (d == 1 ? ay : az)) * sc;
    atomicAdd(out + (size_t)ri * 3 + d, v);
  }
}

extern "C" void kernel_launch(void* const* d_in, const int* in_sizes, int n_in,
                              void* d_out, int out_size, void* d_ws, size_t ws_size,
                              hipStream_t stream) {
  const float* h         = (const float*)d_in[0];
  const float* pos       = (const float*)d_in[1];
  const float* edge_attr = (const float*)d_in[2];
  const float* dist      = (const float*)d_in[3];
  const float* te        = (const float*)d_in[4];
  const float* tW        = (const float*)d_in[5];
  const float* tb        = (const float*)d_in[6];
  const float* iW        = (const float*)d_in[7];
  const float* ib        = (const float*)d_in[8];
  const float* c1W       = (const float*)d_in[9];
  const float* c1b       = (const float*)d_in[10];
  const float* c2W       = (const float*)d_in[11];
  const float* cn        = (const float*)d_in[12];
  const int*   eidx      = (const int*)d_in[13];
  float* out = (float*)d_out;

  char* ws     = (char*)d_ws;
  u16*  wh     = (u16*)(ws);                 // 40000*128*2 = 10,240,000 B
  u16*  wiWt   = (u16*)(ws + 10240000);      // 128*320*2   =     81,920 B
  u16*  wc1Wt  = (u16*)(ws + 10321920);      // 128*128*2   =     32,768 B
  float* film  = (float*)(ws + 10354688);    // 256*4       =      1,024 B

  hipLaunchKernelGGL(prep_h_kernel,    dim3(5000), dim3(256), 0, stream, h, wh);
  hipLaunchKernelGGL(prep_film_kernel, dim3(1),    dim3(256), 0, stream, te, tW, tb, film);
  hipLaunchKernelGGL(prep_tr_kernel,   dim3(160),  dim3(256), 0, stream, iW, wiWt, ICH);
  hipLaunchKernelGGL(prep_tr_kernel,   dim3(64),   dim3(256), 0, stream, c1W, wc1Wt, HD);
  hipLaunchKernelGGL(copy_pos_kernel,  dim3(469),  dim3(256), 0, stream, pos, out);
  hipLaunchKernelGGL(edge_kernel,      dim3(EE / TB), dim3(256), 0, stream,
                     pos, edge_attr, dist, ib, c1b, c2W, cn, eidx,
                     wh, wiWt, wc1Wt, film, out);
}